// Round 7
// baseline (578.904 us; speedup 1.0000x reference)
//
#include <hip/hip_runtime.h>

#define N_NODES 50000
#define N_EDGES 800000
#define EP_EDGES (N_EDGES + N_NODES)
#define N_GRAPHS 256
#define NBLK_SCAN ((N_NODES + 255) / 256)
#define POOL_CHUNK ((N_NODES + 255) / 256)

typedef unsigned short u16;
typedef __attribute__((ext_vector_type(8))) short s8v;    // 8 x bf16 (4 VGPRs)
typedef __attribute__((ext_vector_type(4))) float f4v;    // mfma accumulator

// ---------- bf16 helpers (RNE) ----------
__device__ __forceinline__ u16 fb(float f) {
  unsigned u = __float_as_uint(f);
  return (u16)((u + 0x7fffu + ((u >> 16) & 1u)) >> 16);
}
__device__ __forceinline__ float bfl(unsigned p) {   // low bf16 of packed pair
  return __uint_as_float(p << 16);
}
__device__ __forceinline__ float bfh(unsigned p) {   // high bf16
  return __uint_as_float(p & 0xffff0000u);
}
__device__ __forceinline__ float bff(u16 s) {
  return __uint_as_float(((unsigned)s) << 16);
}

// ---------- fused f32->bf16 conversion of x, W1, W2, W3 ----------
#define F2B_N0 (N_NODES * 128)
#define F2B_N1 (F2B_N0 + 32768)
#define F2B_N2 (F2B_N1 + 65536)
#define F2B_N3 (F2B_N2 + 16384)
__global__ void f2b4(const float* __restrict__ x, const float* __restrict__ w1,
                     const float* __restrict__ w2, const float* __restrict__ w3,
                     u16* __restrict__ xb, u16* __restrict__ w1b,
                     u16* __restrict__ w2b, u16* __restrict__ w3b) {
  int i = blockIdx.x * 256 + threadIdx.x;
  if (i < F2B_N0) xb[i] = fb(x[i]);
  else if (i < F2B_N1) w1b[i - F2B_N0] = fb(w1[i - F2B_N0]);
  else if (i < F2B_N2) w2b[i - F2B_N1] = fb(w2[i - F2B_N1]);
  else if (i < F2B_N3) w3b[i - F2B_N2] = fb(w3[i - F2B_N2]);
}

// ---------- bf16 MFMA GEMM: C[M,Nout](bf16) = A[M,K](bf16) * W[Nout,K](bf16)^T
__global__ __launch_bounds__(256) void gemm_bf16(
    const u16* __restrict__ A, const u16* __restrict__ W,
    u16* __restrict__ C, int M, int Nout, int K) {
  __shared__ u16 As[64][40];
  __shared__ u16 Bs[64][40];
  const int t = threadIdx.x;
  const int m0 = blockIdx.y * 64, n0 = blockIdx.x * 64;
  const int r = t >> 2, c = t & 3;
  const int w = t >> 6, lane = t & 63;
  const int mi = (w & 1) * 32, ni = (w >> 1) * 32;
  const int quad = lane >> 4, fr = lane & 15;

  f4v c00{}, c01{}, c10{}, c11{};
  for (int k0 = 0; k0 < K; k0 += 32) {
    uint4 av = make_uint4(0, 0, 0, 0);
    int m = m0 + r;
    if (m < M) av = *(const uint4*)&A[(size_t)m * K + k0 + c * 8];
    uint4 bv = *(const uint4*)&W[(size_t)(n0 + r) * K + k0 + c * 8];
    __syncthreads();
    *(uint4*)&As[r][c * 8] = av;
    *(uint4*)&Bs[r][c * 8] = bv;
    __syncthreads();
    s8v a0 = *(const s8v*)&As[mi + fr][quad * 8];
    s8v a1 = *(const s8v*)&As[mi + 16 + fr][quad * 8];
    s8v b0 = *(const s8v*)&Bs[ni + fr][quad * 8];
    s8v b1 = *(const s8v*)&Bs[ni + 16 + fr][quad * 8];
    c00 = __builtin_amdgcn_mfma_f32_16x16x32_bf16(a0, b0, c00, 0, 0, 0);
    c01 = __builtin_amdgcn_mfma_f32_16x16x32_bf16(a0, b1, c01, 0, 0, 0);
    c10 = __builtin_amdgcn_mfma_f32_16x16x32_bf16(a1, b0, c10, 0, 0, 0);
    c11 = __builtin_amdgcn_mfma_f32_16x16x32_bf16(a1, b1, c11, 0, 0, 0);
  }
  const int col = n0 + ni + fr;
#pragma unroll
  for (int i = 0; i < 4; ++i) {
    int row = m0 + mi + quad * 4 + i;
    if (row < M) {
      C[(size_t)row * Nout + col] = fb(c00[i]);
      C[(size_t)row * Nout + col + 16] = fb(c01[i]);
    }
    int row2 = row + 16;
    if (row2 < M) {
      C[(size_t)row2 * Nout + col] = fb(c10[i]);
      C[(size_t)row2 * Nout + col + 16] = fb(c11[i]);
    }
  }
}

// ---------- CSR build ----------
__global__ void k_hist(const int* __restrict__ ei, int* __restrict__ deg) {
  int e = blockIdx.x * 256 + threadIdx.x;
  if (e >= EP_EDGES) return;
  int d = (e < N_EDGES) ? ei[N_EDGES + e] : e - N_EDGES;
  atomicAdd(&deg[d], 1);
}

__global__ void k_scan_local(const int* __restrict__ deg,
                             int* __restrict__ rowstart,
                             int* __restrict__ bsum) {
  __shared__ int sh[256];
  const int tid = threadIdx.x;
  const int i = blockIdx.x * 256 + tid;
  int v = (i < N_NODES) ? deg[i] : 0;
  sh[tid] = v;
  __syncthreads();
  for (int off = 1; off < 256; off <<= 1) {
    int add = (tid >= off) ? sh[tid - off] : 0;
    __syncthreads();
    sh[tid] += add;
    __syncthreads();
  }
  if (i < N_NODES) rowstart[i] = sh[tid] - v;
  if (tid == 255) bsum[blockIdx.x] = sh[255];
}

__global__ void k_scan_bsum(int* __restrict__ bsum, int* __restrict__ boff) {
  __shared__ int sh[256];
  const int tid = threadIdx.x;
  int v = (tid < NBLK_SCAN) ? bsum[tid] : 0;
  sh[tid] = v;
  __syncthreads();
  for (int off = 1; off < 256; off <<= 1) {
    int add = (tid >= off) ? sh[tid - off] : 0;
    __syncthreads();
    sh[tid] += add;
    __syncthreads();
  }
  boff[tid] = sh[tid] - v;
}

__global__ void k_scan_add(int* __restrict__ rowstart,
                           const int* __restrict__ boff) {
  int i = blockIdx.x * 256 + threadIdx.x;
  if (i < N_NODES) rowstart[i] += boff[i >> 8];
  if (i == N_NODES) rowstart[N_NODES] = EP_EDGES;
}

__global__ void k_scatter(const int* __restrict__ ei,
                          const int* __restrict__ rowstart,
                          int* __restrict__ fill, int* __restrict__ esrc) {
  int e = blockIdx.x * 256 + threadIdx.x;
  if (e >= EP_EDGES) return;
  int s, d;
  if (e < N_EDGES) { s = ei[e]; d = ei[N_EDGES + e]; }
  else             { s = d = e - N_EDGES; }
  int pos = rowstart[d] + atomicAdd(&fill[d], 1);
  esrc[pos] = s;
}

// ---------- per-node attention scores ----------
__global__ void attn_scores(const u16* __restrict__ h,
                            const float* __restrict__ a_src,
                            const float* __restrict__ a_dst,
                            float* __restrict__ alo, float* __restrict__ ahi,
                            int HC, int H) {
  const int n = blockIdx.x;
  const int t = threadIdx.x;
  float v = bff(h[(size_t)n * HC + t]);
  float s = v * a_src[t];
  float d = v * a_dst[t];
#pragma unroll
  for (int off = 32; off; off >>= 1) {
    s += __shfl_down(s, off, 64);
    d += __shfl_down(d, off, 64);
  }
  if ((t & 63) == 0) {
    int hd = t >> 6;
    alo[n * H + hd] = s;
    ahi[n * H + hd] = d;
  }
}

// ---------- aggregation v3, H=4: one wave per dst, 4 ch/lane, no LDS ----
// Softmax computed WITHOUT max-shift (shift-invariant; scores are O(1)).
__global__ __launch_bounds__(64) void agg3_4(
    const int* __restrict__ rowstart, const int* __restrict__ esrc,
    const u16* __restrict__ hbuf, const float* __restrict__ alo,
    const float* __restrict__ ahi, const float* __restrict__ bias,
    u16* __restrict__ feat) {
  const int d = blockIdx.x;
  const int lane = threadIdx.x;        // 0..63
  const int head = lane >> 4;          // 16 lanes per head
  const int l16 = lane & 15;
  const int c = lane * 4;              // 4 contiguous channels per lane
  const int s0 = rowstart[d], s1 = rowstart[d + 1];
  const float ah = ahi[d * 4 + head];

  // pass A: denom per head
  float sm = 0.f;
  for (int j = s0 + l16; j < s1; j += 16) {
    int s = esrc[j];
    float e = alo[s * 4 + head] + ah;
    e = e > 0.f ? e : 0.2f * e;
    sm += __expf(e);
  }
#pragma unroll
  for (int off = 8; off; off >>= 1) sm += __shfl_xor(sm, off, 64);
  const float linv = 1.f / (sm + 1e-16f);

  // pass B: unroll-4 weighted gather (weight redundant within 16-lane group)
  float o0 = 0.f, o1 = 0.f, o2 = 0.f, o3 = 0.f;
  for (int j = s0; j < s1; j += 4) {
    int ss[4];
    float wq[4];
#pragma unroll
    for (int q = 0; q < 4; ++q) {
      int jj = j + q;
      int sv = esrc[jj < EP_EDGES ? jj : EP_EDGES - 1];
      ss[q] = (jj < s1) ? sv : d;
    }
#pragma unroll
    for (int q = 0; q < 4; ++q) {
      float e = alo[ss[q] * 4 + head] + ah;
      e = e > 0.f ? e : 0.2f * e;
      wq[q] = (j + q < s1) ? __expf(e) * linv : 0.f;
    }
    uint2 hv[4];
#pragma unroll
    for (int q = 0; q < 4; ++q)
      hv[q] = *(const uint2*)&hbuf[(size_t)ss[q] * 256 + c];
#pragma unroll
    for (int q = 0; q < 4; ++q) {
      o0 += wq[q] * bfl(hv[q].x);
      o1 += wq[q] * bfh(hv[q].x);
      o2 += wq[q] * bfl(hv[q].y);
      o3 += wq[q] * bfh(hv[q].y);
    }
  }
  float4 bv = *(const float4*)&bias[c];
  float v0 = o0 + bv.x, v1 = o1 + bv.y, v2 = o2 + bv.z, v3 = o3 + bv.w;
  v0 = v0 > 0.f ? v0 : __expf(v0) - 1.f;
  v1 = v1 > 0.f ? v1 : __expf(v1) - 1.f;
  v2 = v2 > 0.f ? v2 : __expf(v2) - 1.f;
  v3 = v3 > 0.f ? v3 : __expf(v3) - 1.f;
  uint2 pv;
  pv.x = (unsigned)fb(v0) | ((unsigned)fb(v1) << 16);
  pv.y = (unsigned)fb(v2) | ((unsigned)fb(v3) << 16);
  *(uint2*)&feat[(size_t)d * 256 + c] = pv;
}

// ---------- aggregation v3, H=1 (f32 out): one wave per dst ----------
__global__ __launch_bounds__(64) void agg3_1(
    const int* __restrict__ rowstart, const int* __restrict__ esrc,
    const u16* __restrict__ hbuf, const float* __restrict__ alo,
    const float* __restrict__ ahi, const float* __restrict__ bias,
    float* __restrict__ feat) {
  const int d = blockIdx.x;
  const int t = threadIdx.x;
  const int s0 = rowstart[d], s1 = rowstart[d + 1];
  const float ah = ahi[d];

  float sm = 0.f;
  for (int j = s0 + t; j < s1; j += 64) {
    int s = esrc[j];
    float e = alo[s] + ah;
    e = e > 0.f ? e : 0.2f * e;
    sm += __expf(e);
  }
#pragma unroll
  for (int off = 32; off; off >>= 1) sm += __shfl_xor(sm, off, 64);
  const float linv = 1.f / (sm + 1e-16f);

  float o = 0.f;
  for (int j = s0; j < s1; j += 4) {
    int ss[4];
    float wq[4];
#pragma unroll
    for (int q = 0; q < 4; ++q) {
      int jj = j + q;
      int sv = esrc[jj < EP_EDGES ? jj : EP_EDGES - 1];
      ss[q] = (jj < s1) ? sv : d;
    }
#pragma unroll
    for (int q = 0; q < 4; ++q) {
      float e = alo[ss[q]] + ah;
      e = e > 0.f ? e : 0.2f * e;
      wq[q] = (j + q < s1) ? __expf(e) * linv : 0.f;
    }
    u16 hv[4];
#pragma unroll
    for (int q = 0; q < 4; ++q) hv[q] = hbuf[(size_t)ss[q] * 64 + t];
#pragma unroll
    for (int q = 0; q < 4; ++q) o += wq[q] * bff(hv[q]);
  }
  float v = o + bias[t];
  feat[(size_t)d * 64 + t] = v > 0.f ? v : __expf(v) - 1.f;
}

// ---------- segmented global mean pool (batch_idx sorted) ----------
__global__ __launch_bounds__(64) void pool_seg(
    const float* __restrict__ feat, const int* __restrict__ batch,
    float* __restrict__ gsum, float* __restrict__ gcnt) {
  const int b = blockIdx.x;
  const int t = threadIdx.x;
  int n0 = b * POOL_CHUNK;
  int n1 = n0 + POOL_CHUNK;
  if (n1 > N_NODES) n1 = N_NODES;
  if (n0 >= n1) return;
  int g = batch[n0];
  float acc = 0.f;
  int cnt = 0;
  for (int n = n0; n < n1; ++n) {
    int gn = batch[n];
    if (gn != g) {
      atomicAdd(&gsum[g * 64 + t], acc);
      if (t == 0) atomicAdd(&gcnt[g], (float)cnt);
      acc = 0.f; cnt = 0; g = gn;
    }
    acc += feat[(size_t)n * 64 + t];
    ++cnt;
  }
  atomicAdd(&gsum[g * 64 + t], acc);
  if (t == 0) atomicAdd(&gcnt[g], (float)cnt);
}

// ---------- fused MLP heads ----------
__global__ void heads(const float* __restrict__ gsum,
                      const float* __restrict__ gcnt,
                      const float* __restrict__ Wc1, const float* __restrict__ bc1,
                      const float* __restrict__ Wc2, const float* __restrict__ bc2,
                      const float* __restrict__ Wr1, const float* __restrict__ br1,
                      const float* __restrict__ Wr2, const float* __restrict__ br2,
                      float* __restrict__ out) {
  __shared__ float g[64];
  const int gi = blockIdx.x, j = threadIdx.x;
  float cnt = gcnt[gi];
  cnt = cnt < 1.f ? 1.f : cnt;
  g[j] = gsum[gi * 64 + j] / cnt;
  __syncthreads();
  float hc = bc1[j], hr = br1[j];
#pragma unroll 8
  for (int c = 0; c < 64; ++c) {
    float gv = g[c];
    hc += gv * Wc1[j * 64 + c];
    hr += gv * Wr1[j * 64 + c];
  }
  hc = fmaxf(hc, 0.f) * Wc2[j];
  hr = fmaxf(hr, 0.f) * Wr2[j];
#pragma unroll
  for (int off = 32; off; off >>= 1) {
    hc += __shfl_down(hc, off, 64);
    hr += __shfl_down(hr, off, 64);
  }
  if (j == 0) {
    out[gi] = hc + bc2[0];
    out[N_GRAPHS + gi] = hr + br2[0];
  }
}

extern "C" void kernel_launch(void* const* d_in, const int* in_sizes, int n_in,
                              void* d_out, int out_size, void* d_ws,
                              size_t ws_size, hipStream_t stream) {
  const float* x   = (const float*)d_in[0];
  const int* ei    = (const int*)d_in[1];
  const int* batch = (const int*)d_in[2];
  const float* W1  = (const float*)d_in[3];
  const float* as1 = (const float*)d_in[4];
  const float* ad1 = (const float*)d_in[5];
  const float* b1  = (const float*)d_in[6];
  const float* W2  = (const float*)d_in[7];
  const float* as2 = (const float*)d_in[8];
  const float* ad2 = (const float*)d_in[9];
  const float* b2  = (const float*)d_in[10];
  const float* W3  = (const float*)d_in[11];
  const float* as3 = (const float*)d_in[12];
  const float* ad3 = (const float*)d_in[13];
  const float* b3  = (const float*)d_in[14];
  const float* Wc1 = (const float*)d_in[15];
  const float* bc1 = (const float*)d_in[16];
  const float* Wc2 = (const float*)d_in[17];
  const float* bc2 = (const float*)d_in[18];
  const float* Wr1 = (const float*)d_in[19];
  const float* br1 = (const float*)d_in[20];
  const float* Wr2 = (const float*)d_in[21];
  const float* br2 = (const float*)d_in[22];
  float* out = (float*)d_out;

  // ---- workspace layout ----
  float* ws = (float*)d_ws;
  u16* h_buf = (u16*)ws;
  float* p = ws + (size_t)N_NODES * 128;
  u16* featb = (u16*)p;
  p += (size_t)N_NODES * 128;
  u16* xb = (u16*)p;
  p += (size_t)N_NODES * 64;
  u16* W1b = (u16*)p; p += 16384;
  u16* W2b = (u16*)p; p += 32768;
  u16* W3b = (u16*)p; p += 8192;
  float* feat3 = p;   p += (size_t)N_NODES * 64;
  float* alo   = p;   p += (size_t)N_NODES * 4;
  float* ahi   = p;   p += (size_t)N_NODES * 4;
  int* rowstart = (int*)p; p += (N_NODES + 4);
  int* esrc    = (int*)p;  p += EP_EDGES;
  float* gsum  = p;   p += N_GRAPHS * 64;
  float* gcnt  = p;
  int* deg  = (int*)alo;                 // [N]
  int* fill = (int*)alo + N_NODES;       // [N] adjacent -> single memset
  int* bsum = (int*)gsum;
  int* boff = (int*)gsum + 256;

  // ---- CSR build ----
  hipMemsetAsync(deg, 0, (size_t)2 * N_NODES * 4, stream);  // deg + fill
  const int eblk = (EP_EDGES + 255) / 256;
  k_hist<<<eblk, 256, 0, stream>>>(ei, deg);
  k_scan_local<<<NBLK_SCAN, 256, 0, stream>>>(deg, rowstart, bsum);
  k_scan_bsum<<<1, 256, 0, stream>>>(bsum, boff);
  k_scan_add<<<(N_NODES + 256) / 256, 256, 0, stream>>>(rowstart, boff);
  k_scatter<<<eblk, 256, 0, stream>>>(ei, rowstart, fill, esrc);

  // ---- input/weight bf16 conversion (single launch) ----
  f2b4<<<(F2B_N3 + 255) / 256, 256, 0, stream>>>(x, W1, W2, W3, xb, W1b, W2b,
                                                 W3b);

  const int MB = (N_NODES + 63) / 64;
  // ---- layer 1 ----
  gemm_bf16<<<dim3(4, MB), 256, 0, stream>>>(xb, W1b, h_buf, N_NODES, 256, 128);
  attn_scores<<<N_NODES, 256, 0, stream>>>(h_buf, as1, ad1, alo, ahi, 256, 4);
  agg3_4<<<N_NODES, 64, 0, stream>>>(rowstart, esrc, h_buf, alo, ahi, b1,
                                     featb);
  // ---- layer 2 ----
  gemm_bf16<<<dim3(4, MB), 256, 0, stream>>>(featb, W2b, h_buf, N_NODES, 256, 256);
  attn_scores<<<N_NODES, 256, 0, stream>>>(h_buf, as2, ad2, alo, ahi, 256, 4);
  agg3_4<<<N_NODES, 64, 0, stream>>>(rowstart, esrc, h_buf, alo, ahi, b2,
                                     featb);
  // ---- layer 3 ----
  gemm_bf16<<<dim3(1, MB), 256, 0, stream>>>(featb, W3b, h_buf, N_NODES, 64, 256);
  attn_scores<<<N_NODES, 64, 0, stream>>>(h_buf, as3, ad3, alo, ahi, 64, 1);
  agg3_1<<<N_NODES, 64, 0, stream>>>(rowstart, esrc, h_buf, alo, ahi, b3,
                                     feat3);

  // ---- segmented mean pool + heads ----
  hipMemsetAsync(gsum, 0, (size_t)(N_GRAPHS * 64 + N_GRAPHS) * 4, stream);
  pool_seg<<<N_GRAPHS, 64, 0, stream>>>(feat3, batch, gsum, gcnt);
  heads<<<N_GRAPHS, 64, 0, stream>>>(gsum, gcnt, Wc1, bc1, Wc2, bc2, Wr1, br1,
                                     Wr2, br2, out);
}

// Round 8
// 562.719 us; speedup vs baseline: 1.0288x; 1.0288x over previous
//
#include <hip/hip_runtime.h>

#define N_NODES 50000
#define N_EDGES 800000
#define EP_EDGES (N_EDGES + N_NODES)
#define N_GRAPHS 256
#define NBLK_SCAN ((N_NODES + 255) / 256)
#define POOL_CHUNK ((N_NODES + 255) / 256)

typedef unsigned short u16;
typedef __attribute__((ext_vector_type(8))) short s8v;    // 8 x bf16 (4 VGPRs)
typedef __attribute__((ext_vector_type(4))) float f4v;    // mfma accumulator

// ---------- bf16 helpers (RNE) ----------
__device__ __forceinline__ u16 fb(float f) {
  unsigned u = __float_as_uint(f);
  return (u16)((u + 0x7fffu + ((u >> 16) & 1u)) >> 16);
}
__device__ __forceinline__ float bfl(unsigned p) {
  return __uint_as_float(p << 16);
}
__device__ __forceinline__ float bfh(unsigned p) {
  return __uint_as_float(p & 0xffff0000u);
}
__device__ __forceinline__ float bff(u16 s) {
  return __uint_as_float(((unsigned)s) << 16);
}

// ---------- fused f32->bf16 conversion of x, W1, W2, W3 ----------
#define F2B_N0 (N_NODES * 128)
#define F2B_N1 (F2B_N0 + 32768)
#define F2B_N2 (F2B_N1 + 65536)
#define F2B_N3 (F2B_N2 + 16384)
__global__ void f2b4(const float* __restrict__ x, const float* __restrict__ w1,
                     const float* __restrict__ w2, const float* __restrict__ w3,
                     u16* __restrict__ xb, u16* __restrict__ w1b,
                     u16* __restrict__ w2b, u16* __restrict__ w3b) {
  int i = blockIdx.x * 256 + threadIdx.x;
  if (i < F2B_N0) xb[i] = fb(x[i]);
  else if (i < F2B_N1) w1b[i - F2B_N0] = fb(w1[i - F2B_N0]);
  else if (i < F2B_N2) w2b[i - F2B_N1] = fb(w2[i - F2B_N1]);
  else if (i < F2B_N3) w3b[i - F2B_N2] = fb(w3[i - F2B_N2]);
}

// ---------- 128x128-tile bf16 MFMA GEMM (layers 1&2; Nout % 128 == 0) ----
// 4 waves in 2x2; each wave 64x64 via 4x4 of 16x16x32 mfma.
__global__ __launch_bounds__(256) void gemm128(
    const u16* __restrict__ A, const u16* __restrict__ W,
    u16* __restrict__ C, int M, int Nout, int K) {
  __shared__ u16 As[128][40];  // 32-elem K-chunk + 8 pad: 80B row stride
  __shared__ u16 Bs[128][40];
  const int t = threadIdx.x;
  const int m0 = blockIdx.y * 128, n0 = blockIdx.x * 128;
  const int rq = t >> 2, q = t & 3;          // staging: row, 8-elem quarter
  const int w = t >> 6, lane = t & 63;
  const int wi = (w & 1) * 64, wj = (w >> 1) * 64;
  const int quad = lane >> 4, fr = lane & 15;

  f4v acc[4][4] = {};
  for (int k0 = 0; k0 < K; k0 += 32) {
    uint4 av[2], bv[2];
#pragma unroll
    for (int g = 0; g < 2; ++g) {
      int r = rq + g * 64;
      int m = m0 + r;
      av[g] = (m < M) ? *(const uint4*)&A[(size_t)m * K + k0 + q * 8]
                      : make_uint4(0, 0, 0, 0);
      bv[g] = *(const uint4*)&W[(size_t)(n0 + r) * K + k0 + q * 8];
    }
    __syncthreads();
#pragma unroll
    for (int g = 0; g < 2; ++g) {
      *(uint4*)&As[rq + g * 64][q * 8] = av[g];
      *(uint4*)&Bs[rq + g * 64][q * 8] = bv[g];
    }
    __syncthreads();
    s8v af[4], bf_[4];
#pragma unroll
    for (int i = 0; i < 4; ++i) {
      af[i] = *(const s8v*)&As[wi + i * 16 + fr][quad * 8];
      bf_[i] = *(const s8v*)&Bs[wj + i * 16 + fr][quad * 8];
    }
#pragma unroll
    for (int i = 0; i < 4; ++i)
#pragma unroll
      for (int j = 0; j < 4; ++j)
        acc[i][j] =
            __builtin_amdgcn_mfma_f32_16x16x32_bf16(af[i], bf_[j], acc[i][j], 0, 0, 0);
  }
  // C/D layout: col = fr, row = quad*4 + reg
#pragma unroll
  for (int i = 0; i < 4; ++i) {
    int rbase = m0 + wi + i * 16 + quad * 4;
#pragma unroll
    for (int j = 0; j < 4; ++j) {
      int col = n0 + wj + j * 16 + fr;
#pragma unroll
      for (int r = 0; r < 4; ++r) {
        int row = rbase + r;
        if (row < M) C[(size_t)row * Nout + col] = fb(acc[i][j][r]);
      }
    }
  }
}

// ---------- 64x64-tile GEMM (layer 3, Nout=64) ----------
__global__ __launch_bounds__(256) void gemm_bf16(
    const u16* __restrict__ A, const u16* __restrict__ W,
    u16* __restrict__ C, int M, int Nout, int K) {
  __shared__ u16 As[64][40];
  __shared__ u16 Bs[64][40];
  const int t = threadIdx.x;
  const int m0 = blockIdx.y * 64, n0 = blockIdx.x * 64;
  const int r = t >> 2, c = t & 3;
  const int w = t >> 6, lane = t & 63;
  const int mi = (w & 1) * 32, ni = (w >> 1) * 32;
  const int quad = lane >> 4, fr = lane & 15;

  f4v c00{}, c01{}, c10{}, c11{};
  for (int k0 = 0; k0 < K; k0 += 32) {
    uint4 av = make_uint4(0, 0, 0, 0);
    int m = m0 + r;
    if (m < M) av = *(const uint4*)&A[(size_t)m * K + k0 + c * 8];
    uint4 bv = *(const uint4*)&W[(size_t)(n0 + r) * K + k0 + c * 8];
    __syncthreads();
    *(uint4*)&As[r][c * 8] = av;
    *(uint4*)&Bs[r][c * 8] = bv;
    __syncthreads();
    s8v a0 = *(const s8v*)&As[mi + fr][quad * 8];
    s8v a1 = *(const s8v*)&As[mi + 16 + fr][quad * 8];
    s8v b0 = *(const s8v*)&Bs[ni + fr][quad * 8];
    s8v b1 = *(const s8v*)&Bs[ni + 16 + fr][quad * 8];
    c00 = __builtin_amdgcn_mfma_f32_16x16x32_bf16(a0, b0, c00, 0, 0, 0);
    c01 = __builtin_amdgcn_mfma_f32_16x16x32_bf16(a0, b1, c01, 0, 0, 0);
    c10 = __builtin_amdgcn_mfma_f32_16x16x32_bf16(a1, b0, c10, 0, 0, 0);
    c11 = __builtin_amdgcn_mfma_f32_16x16x32_bf16(a1, b1, c11, 0, 0, 0);
  }
  const int col = n0 + ni + fr;
#pragma unroll
  for (int i = 0; i < 4; ++i) {
    int row = m0 + mi + quad * 4 + i;
    if (row < M) {
      C[(size_t)row * Nout + col] = fb(c00[i]);
      C[(size_t)row * Nout + col + 16] = fb(c01[i]);
    }
    int row2 = row + 16;
    if (row2 < M) {
      C[(size_t)row2 * Nout + col] = fb(c10[i]);
      C[(size_t)row2 * Nout + col + 16] = fb(c11[i]);
    }
  }
}

// ---------- CSR build ----------
__global__ void k_hist(const int* __restrict__ ei, int* __restrict__ deg) {
  int e = blockIdx.x * 256 + threadIdx.x;
  if (e >= EP_EDGES) return;
  int d = (e < N_EDGES) ? ei[N_EDGES + e] : e - N_EDGES;
  atomicAdd(&deg[d], 1);
}

__global__ void k_scan_local(const int* __restrict__ deg,
                             int* __restrict__ rowstart,
                             int* __restrict__ bsum) {
  __shared__ int sh[256];
  const int tid = threadIdx.x;
  const int i = blockIdx.x * 256 + tid;
  int v = (i < N_NODES) ? deg[i] : 0;
  sh[tid] = v;
  __syncthreads();
  for (int off = 1; off < 256; off <<= 1) {
    int add = (tid >= off) ? sh[tid - off] : 0;
    __syncthreads();
    sh[tid] += add;
    __syncthreads();
  }
  if (i < N_NODES) rowstart[i] = sh[tid] - v;
  if (tid == 255) bsum[blockIdx.x] = sh[255];
}

__global__ void k_scan_bsum(int* __restrict__ bsum, int* __restrict__ boff) {
  __shared__ int sh[256];
  const int tid = threadIdx.x;
  int v = (tid < NBLK_SCAN) ? bsum[tid] : 0;
  sh[tid] = v;
  __syncthreads();
  for (int off = 1; off < 256; off <<= 1) {
    int add = (tid >= off) ? sh[tid - off] : 0;
    __syncthreads();
    sh[tid] += add;
    __syncthreads();
  }
  boff[tid] = sh[tid] - v;
}

__global__ void k_scan_add(int* __restrict__ rowstart,
                           const int* __restrict__ boff) {
  int i = blockIdx.x * 256 + threadIdx.x;
  if (i < N_NODES) rowstart[i] += boff[i >> 8];
  if (i == N_NODES) rowstart[N_NODES] = EP_EDGES;
}

__global__ void k_scatter(const int* __restrict__ ei,
                          const int* __restrict__ rowstart,
                          int* __restrict__ fill, int* __restrict__ esrc) {
  int e = blockIdx.x * 256 + threadIdx.x;
  if (e >= EP_EDGES) return;
  int s, d;
  if (e < N_EDGES) { s = ei[e]; d = ei[N_EDGES + e]; }
  else             { s = d = e - N_EDGES; }
  int pos = rowstart[d] + atomicAdd(&fill[d], 1);
  esrc[pos] = s;
}

// ---------- per-node attention scores, H=4: wave per node, uint2 loads ----
__global__ __launch_bounds__(256) void attn_scores4(
    const u16* __restrict__ h, const float* __restrict__ a_src,
    const float* __restrict__ a_dst, float* __restrict__ alo,
    float* __restrict__ ahi) {
  const int t = threadIdx.x;
  const int n = blockIdx.x * 4 + (t >> 6);
  const int lane = t & 63;
  const int head = lane >> 4, l16 = lane & 15;
  const int ch = head * 64 + l16 * 4;
  uint2 hv = *(const uint2*)&h[(size_t)n * 256 + ch];
  float4 asv = *(const float4*)&a_src[ch];
  float4 adv = *(const float4*)&a_dst[ch];
  float v0 = bfl(hv.x), v1 = bfh(hv.x), v2 = bfl(hv.y), v3 = bfh(hv.y);
  float s = v0 * asv.x + v1 * asv.y + v2 * asv.z + v3 * asv.w;
  float d = v0 * adv.x + v1 * adv.y + v2 * adv.z + v3 * adv.w;
#pragma unroll
  for (int off = 8; off; off >>= 1) {
    s += __shfl_xor(s, off, 64);
    d += __shfl_xor(d, off, 64);
  }
  if (l16 == 0) {
    alo[n * 4 + head] = s;
    ahi[n * 4 + head] = d;
  }
}

// ---------- per-node attention scores, H=1: wave per node ----------
__global__ __launch_bounds__(256) void attn_scores1(
    const u16* __restrict__ h, const float* __restrict__ a_src,
    const float* __restrict__ a_dst, float* __restrict__ alo,
    float* __restrict__ ahi) {
  const int t = threadIdx.x;
  const int n = blockIdx.x * 4 + (t >> 6);
  const int lane = t & 63;
  float v = bff(h[(size_t)n * 64 + lane]);
  float s = v * a_src[lane];
  float d = v * a_dst[lane];
#pragma unroll
  for (int off = 32; off; off >>= 1) {
    s += __shfl_xor(s, off, 64);
    d += __shfl_xor(d, off, 64);
  }
  if (lane == 0) {
    alo[n] = s;
    ahi[n] = d;
  }
}

// ---------- aggregation v3, H=4: one wave per dst, 4 ch/lane, no LDS ----
__global__ __launch_bounds__(64) void agg3_4(
    const int* __restrict__ rowstart, const int* __restrict__ esrc,
    const u16* __restrict__ hbuf, const float* __restrict__ alo,
    const float* __restrict__ ahi, const float* __restrict__ bias,
    u16* __restrict__ feat) {
  const int d = blockIdx.x;
  const int lane = threadIdx.x;
  const int head = lane >> 4;
  const int l16 = lane & 15;
  const int c = lane * 4;
  const int s0 = rowstart[d], s1 = rowstart[d + 1];
  const float ah = ahi[d * 4 + head];

  float sm = 0.f;
  for (int j = s0 + l16; j < s1; j += 16) {
    int s = esrc[j];
    float e = alo[s * 4 + head] + ah;
    e = e > 0.f ? e : 0.2f * e;
    sm += __expf(e);
  }
#pragma unroll
  for (int off = 8; off; off >>= 1) sm += __shfl_xor(sm, off, 64);
  const float linv = 1.f / (sm + 1e-16f);

  float o0 = 0.f, o1 = 0.f, o2 = 0.f, o3 = 0.f;
  for (int j = s0; j < s1; j += 4) {
    int ss[4];
    float wq[4];
#pragma unroll
    for (int q = 0; q < 4; ++q) {
      int jj = j + q;
      int sv = esrc[jj < EP_EDGES ? jj : EP_EDGES - 1];
      ss[q] = (jj < s1) ? sv : d;
    }
#pragma unroll
    for (int q = 0; q < 4; ++q) {
      float e = alo[ss[q] * 4 + head] + ah;
      e = e > 0.f ? e : 0.2f * e;
      wq[q] = (j + q < s1) ? __expf(e) * linv : 0.f;
    }
    uint2 hv[4];
#pragma unroll
    for (int q = 0; q < 4; ++q)
      hv[q] = *(const uint2*)&hbuf[(size_t)ss[q] * 256 + c];
#pragma unroll
    for (int q = 0; q < 4; ++q) {
      o0 += wq[q] * bfl(hv[q].x);
      o1 += wq[q] * bfh(hv[q].x);
      o2 += wq[q] * bfl(hv[q].y);
      o3 += wq[q] * bfh(hv[q].y);
    }
  }
  float4 bv = *(const float4*)&bias[c];
  float v0 = o0 + bv.x, v1 = o1 + bv.y, v2 = o2 + bv.z, v3 = o3 + bv.w;
  v0 = v0 > 0.f ? v0 : __expf(v0) - 1.f;
  v1 = v1 > 0.f ? v1 : __expf(v1) - 1.f;
  v2 = v2 > 0.f ? v2 : __expf(v2) - 1.f;
  v3 = v3 > 0.f ? v3 : __expf(v3) - 1.f;
  uint2 pv;
  pv.x = (unsigned)fb(v0) | ((unsigned)fb(v1) << 16);
  pv.y = (unsigned)fb(v2) | ((unsigned)fb(v3) << 16);
  *(uint2*)&feat[(size_t)d * 256 + c] = pv;
}

// ---------- aggregation v3, H=1 (f32 out) ----------
__global__ __launch_bounds__(64) void agg3_1(
    const int* __restrict__ rowstart, const int* __restrict__ esrc,
    const u16* __restrict__ hbuf, const float* __restrict__ alo,
    const float* __restrict__ ahi, const float* __restrict__ bias,
    float* __restrict__ feat) {
  const int d = blockIdx.x;
  const int t = threadIdx.x;
  const int s0 = rowstart[d], s1 = rowstart[d + 1];
  const float ah = ahi[d];

  float sm = 0.f;
  for (int j = s0 + t; j < s1; j += 64) {
    int s = esrc[j];
    float e = alo[s] + ah;
    e = e > 0.f ? e : 0.2f * e;
    sm += __expf(e);
  }
#pragma unroll
  for (int off = 32; off; off >>= 1) sm += __shfl_xor(sm, off, 64);
  const float linv = 1.f / (sm + 1e-16f);

  float o = 0.f;
  for (int j = s0; j < s1; j += 4) {
    int ss[4];
    float wq[4];
#pragma unroll
    for (int q = 0; q < 4; ++q) {
      int jj = j + q;
      int sv = esrc[jj < EP_EDGES ? jj : EP_EDGES - 1];
      ss[q] = (jj < s1) ? sv : d;
    }
#pragma unroll
    for (int q = 0; q < 4; ++q) {
      float e = alo[ss[q]] + ah;
      e = e > 0.f ? e : 0.2f * e;
      wq[q] = (j + q < s1) ? __expf(e) * linv : 0.f;
    }
    u16 hv[4];
#pragma unroll
    for (int q = 0; q < 4; ++q) hv[q] = hbuf[(size_t)ss[q] * 64 + t];
#pragma unroll
    for (int q = 0; q < 4; ++q) o += wq[q] * bff(hv[q]);
  }
  float v = o + bias[t];
  feat[(size_t)d * 64 + t] = v > 0.f ? v : __expf(v) - 1.f;
}

// ---------- segmented global mean pool (batch_idx sorted) ----------
__global__ __launch_bounds__(64) void pool_seg(
    const float* __restrict__ feat, const int* __restrict__ batch,
    float* __restrict__ gsum, float* __restrict__ gcnt) {
  const int b = blockIdx.x;
  const int t = threadIdx.x;
  int n0 = b * POOL_CHUNK;
  int n1 = n0 + POOL_CHUNK;
  if (n1 > N_NODES) n1 = N_NODES;
  if (n0 >= n1) return;
  int g = batch[n0];
  float acc = 0.f;
  int cnt = 0;
  for (int n = n0; n < n1; ++n) {
    int gn = batch[n];
    if (gn != g) {
      atomicAdd(&gsum[g * 64 + t], acc);
      if (t == 0) atomicAdd(&gcnt[g], (float)cnt);
      acc = 0.f; cnt = 0; g = gn;
    }
    acc += feat[(size_t)n * 64 + t];
    ++cnt;
  }
  atomicAdd(&gsum[g * 64 + t], acc);
  if (t == 0) atomicAdd(&gcnt[g], (float)cnt);
}

// ---------- fused MLP heads ----------
__global__ void heads(const float* __restrict__ gsum,
                      const float* __restrict__ gcnt,
                      const float* __restrict__ Wc1, const float* __restrict__ bc1,
                      const float* __restrict__ Wc2, const float* __restrict__ bc2,
                      const float* __restrict__ Wr1, const float* __restrict__ br1,
                      const float* __restrict__ Wr2, const float* __restrict__ br2,
                      float* __restrict__ out) {
  __shared__ float g[64];
  const int gi = blockIdx.x, j = threadIdx.x;
  float cnt = gcnt[gi];
  cnt = cnt < 1.f ? 1.f : cnt;
  g[j] = gsum[gi * 64 + j] / cnt;
  __syncthreads();
  float hc = bc1[j], hr = br1[j];
#pragma unroll 8
  for (int c = 0; c < 64; ++c) {
    float gv = g[c];
    hc += gv * Wc1[j * 64 + c];
    hr += gv * Wr1[j * 64 + c];
  }
  hc = fmaxf(hc, 0.f) * Wc2[j];
  hr = fmaxf(hr, 0.f) * Wr2[j];
#pragma unroll
  for (int off = 32; off; off >>= 1) {
    hc += __shfl_down(hc, off, 64);
    hr += __shfl_down(hr, off, 64);
  }
  if (j == 0) {
    out[gi] = hc + bc2[0];
    out[N_GRAPHS + gi] = hr + br2[0];
  }
}

extern "C" void kernel_launch(void* const* d_in, const int* in_sizes, int n_in,
                              void* d_out, int out_size, void* d_ws,
                              size_t ws_size, hipStream_t stream) {
  const float* x   = (const float*)d_in[0];
  const int* ei    = (const int*)d_in[1];
  const int* batch = (const int*)d_in[2];
  const float* W1  = (const float*)d_in[3];
  const float* as1 = (const float*)d_in[4];
  const float* ad1 = (const float*)d_in[5];
  const float* b1  = (const float*)d_in[6];
  const float* W2  = (const float*)d_in[7];
  const float* as2 = (const float*)d_in[8];
  const float* ad2 = (const float*)d_in[9];
  const float* b2  = (const float*)d_in[10];
  const float* W3  = (const float*)d_in[11];
  const float* as3 = (const float*)d_in[12];
  const float* ad3 = (const float*)d_in[13];
  const float* b3  = (const float*)d_in[14];
  const float* Wc1 = (const float*)d_in[15];
  const float* bc1 = (const float*)d_in[16];
  const float* Wc2 = (const float*)d_in[17];
  const float* bc2 = (const float*)d_in[18];
  const float* Wr1 = (const float*)d_in[19];
  const float* br1 = (const float*)d_in[20];
  const float* Wr2 = (const float*)d_in[21];
  const float* br2 = (const float*)d_in[22];
  float* out = (float*)d_out;

  // ---- workspace layout ----
  float* ws = (float*)d_ws;
  u16* h_buf = (u16*)ws;
  float* p = ws + (size_t)N_NODES * 128;
  u16* featb = (u16*)p;
  p += (size_t)N_NODES * 128;
  u16* xb = (u16*)p;
  p += (size_t)N_NODES * 64;
  u16* W1b = (u16*)p; p += 16384;
  u16* W2b = (u16*)p; p += 32768;
  u16* W3b = (u16*)p; p += 8192;
  float* feat3 = p;   p += (size_t)N_NODES * 64;
  float* alo   = p;   p += (size_t)N_NODES * 4;
  float* ahi   = p;   p += (size_t)N_NODES * 4;
  int* rowstart = (int*)p; p += (N_NODES + 4);
  int* esrc    = (int*)p;  p += EP_EDGES;
  float* gsum  = p;   p += N_GRAPHS * 64;
  float* gcnt  = p;
  int* deg  = (int*)alo;
  int* fill = (int*)alo + N_NODES;
  int* bsum = (int*)gsum;
  int* boff = (int*)gsum + 256;

  // ---- CSR build ----
  hipMemsetAsync(deg, 0, (size_t)2 * N_NODES * 4, stream);  // deg + fill
  const int eblk = (EP_EDGES + 255) / 256;
  k_hist<<<eblk, 256, 0, stream>>>(ei, deg);
  k_scan_local<<<NBLK_SCAN, 256, 0, stream>>>(deg, rowstart, bsum);
  k_scan_bsum<<<1, 256, 0, stream>>>(bsum, boff);
  k_scan_add<<<(N_NODES + 256) / 256, 256, 0, stream>>>(rowstart, boff);
  k_scatter<<<eblk, 256, 0, stream>>>(ei, rowstart, fill, esrc);

  // ---- input/weight bf16 conversion ----
  f2b4<<<(F2B_N3 + 255) / 256, 256, 0, stream>>>(x, W1, W2, W3, xb, W1b, W2b,
                                                 W3b);

  const int MB128 = (N_NODES + 127) / 128;
  const int MB64 = (N_NODES + 63) / 64;
  // ---- layer 1 ----
  gemm128<<<dim3(2, MB128), 256, 0, stream>>>(xb, W1b, h_buf, N_NODES, 256, 128);
  attn_scores4<<<N_NODES / 4, 256, 0, stream>>>(h_buf, as1, ad1, alo, ahi);
  agg3_4<<<N_NODES, 64, 0, stream>>>(rowstart, esrc, h_buf, alo, ahi, b1,
                                     featb);
  // ---- layer 2 ----
  gemm128<<<dim3(2, MB128), 256, 0, stream>>>(featb, W2b, h_buf, N_NODES, 256, 256);
  attn_scores4<<<N_NODES / 4, 256, 0, stream>>>(h_buf, as2, ad2, alo, ahi);
  agg3_4<<<N_NODES, 64, 0, stream>>>(rowstart, esrc, h_buf, alo, ahi, b2,
                                     featb);
  // ---- layer 3 ----
  gemm_bf16<<<dim3(1, MB64), 256, 0, stream>>>(featb, W3b, h_buf, N_NODES, 64, 256);
  attn_scores1<<<N_NODES / 4, 256, 0, stream>>>(h_buf, as3, ad3, alo, ahi);
  agg3_1<<<N_NODES, 64, 0, stream>>>(rowstart, esrc, h_buf, alo, ahi, b3,
                                     feat3);

  // ---- segmented mean pool + heads ----
  hipMemsetAsync(gsum, 0, (size_t)(N_GRAPHS * 64 + N_GRAPHS) * 4, stream);
  pool_seg<<<N_GRAPHS, 64, 0, stream>>>(feat3, batch, gsum, gcnt);
  heads<<<N_GRAPHS, 64, 0, stream>>>(gsum, gcnt, Wc1, bc1, Wc2, bc2, Wr1, br1,
                                     Wr2, br2, out);
}

// Round 9
// 558.701 us; speedup vs baseline: 1.0362x; 1.0072x over previous
//
#include <hip/hip_runtime.h>

#define N_NODES 50000
#define N_EDGES 800000
#define EP_EDGES (N_EDGES + N_NODES)
#define N_GRAPHS 256
#define NBLK_SCAN ((N_NODES + 255) / 256)
#define POOL_CHUNK ((N_NODES + 255) / 256)

typedef unsigned short u16;
typedef __attribute__((ext_vector_type(8))) short s8v;    // 8 x bf16 (4 VGPRs)
typedef __attribute__((ext_vector_type(4))) float f4v;    // mfma accumulator

// ---------- bf16 helpers (RNE) ----------
__device__ __forceinline__ u16 fb(float f) {
  unsigned u = __float_as_uint(f);
  return (u16)((u + 0x7fffu + ((u >> 16) & 1u)) >> 16);
}
__device__ __forceinline__ float bfl(unsigned p) {
  return __uint_as_float(p << 16);
}
__device__ __forceinline__ float bfh(unsigned p) {
  return __uint_as_float(p & 0xffff0000u);
}
__device__ __forceinline__ float bff(u16 s) {
  return __uint_as_float(((unsigned)s) << 16);
}

// ---------- f32->bf16 conversion of W1, W2, W3 (weights only) ----------
#define W_N1 32768
#define W_N2 (W_N1 + 65536)
#define W_N3 (W_N2 + 16384)
__global__ void f2bw(const float* __restrict__ w1, const float* __restrict__ w2,
                     const float* __restrict__ w3, u16* __restrict__ w1b,
                     u16* __restrict__ w2b, u16* __restrict__ w3b) {
  int i = blockIdx.x * 256 + threadIdx.x;
  if (i < W_N1) w1b[i] = fb(w1[i]);
  else if (i < W_N2) w2b[i - W_N1] = fb(w2[i - W_N1]);
  else if (i < W_N3) w3b[i - W_N2] = fb(w3[i - W_N2]);
}

// ---------- fused attn-score epilogue (gemm128 family) ----------
// wave covers rows m0+wi+{i*16+quad*4+r}, cols n0+wj+{j*16+fr} = one head.
__device__ __forceinline__ void score_epilogue(
    f4v (&acc)[4][4], const float* __restrict__ a_src,
    const float* __restrict__ a_dst, float* __restrict__ alo,
    float* __restrict__ ahi, int m0, int n0, int wi, int wj, int quad, int fr,
    int M) {
  const int head = (n0 + wj) >> 6;
  float as[4], ad[4];
#pragma unroll
  for (int j = 0; j < 4; ++j) {
    int col = n0 + wj + j * 16 + fr;
    as[j] = a_src[col];
    ad[j] = a_dst[col];
  }
#pragma unroll
  for (int i = 0; i < 4; ++i) {
#pragma unroll
    for (int r = 0; r < 4; ++r) {
      float s = 0.f, d = 0.f;
#pragma unroll
      for (int j = 0; j < 4; ++j) {
        s += acc[i][j][r] * as[j];
        d += acc[i][j][r] * ad[j];
      }
#pragma unroll
      for (int off = 8; off; off >>= 1) {
        s += __shfl_xor(s, off, 64);
        d += __shfl_xor(d, off, 64);
      }
      int row = m0 + wi + i * 16 + quad * 4 + r;
      if (fr == 0 && row < M) {
        alo[row * 4 + head] = s;
        ahi[row * 4 + head] = d;
      }
    }
  }
}

// ---------- 128x128-tile bf16 GEMM + fused scores (layer 2) ----------
__global__ __launch_bounds__(256) void gemm128(
    const u16* __restrict__ A, const u16* __restrict__ W,
    u16* __restrict__ C, const float* __restrict__ a_src,
    const float* __restrict__ a_dst, float* __restrict__ alo,
    float* __restrict__ ahi, int M, int Nout, int K) {
  __shared__ u16 As[128][40];
  __shared__ u16 Bs[128][40];
  const int t = threadIdx.x;
  const int m0 = blockIdx.y * 128, n0 = blockIdx.x * 128;
  const int rq = t >> 2, q = t & 3;
  const int w = t >> 6, lane = t & 63;
  const int wi = (w & 1) * 64, wj = (w >> 1) * 64;
  const int quad = lane >> 4, fr = lane & 15;

  f4v acc[4][4] = {};
  for (int k0 = 0; k0 < K; k0 += 32) {
    uint4 av[2], bv[2];
#pragma unroll
    for (int g = 0; g < 2; ++g) {
      int r = rq + g * 64;
      int m = m0 + r;
      av[g] = (m < M) ? *(const uint4*)&A[(size_t)m * K + k0 + q * 8]
                      : make_uint4(0, 0, 0, 0);
      bv[g] = *(const uint4*)&W[(size_t)(n0 + r) * K + k0 + q * 8];
    }
    __syncthreads();
#pragma unroll
    for (int g = 0; g < 2; ++g) {
      *(uint4*)&As[rq + g * 64][q * 8] = av[g];
      *(uint4*)&Bs[rq + g * 64][q * 8] = bv[g];
    }
    __syncthreads();
    s8v af[4], bf_[4];
#pragma unroll
    for (int i = 0; i < 4; ++i) {
      af[i] = *(const s8v*)&As[wi + i * 16 + fr][quad * 8];
      bf_[i] = *(const s8v*)&Bs[wj + i * 16 + fr][quad * 8];
    }
#pragma unroll
    for (int i = 0; i < 4; ++i)
#pragma unroll
      for (int j = 0; j < 4; ++j)
        acc[i][j] =
            __builtin_amdgcn_mfma_f32_16x16x32_bf16(af[i], bf_[j], acc[i][j], 0, 0, 0);
  }
#pragma unroll
  for (int i = 0; i < 4; ++i) {
    int rbase = m0 + wi + i * 16 + quad * 4;
#pragma unroll
    for (int j = 0; j < 4; ++j) {
      int col = n0 + wj + j * 16 + fr;
#pragma unroll
      for (int r = 0; r < 4; ++r) {
        int row = rbase + r;
        if (row < M) C[(size_t)row * Nout + col] = fb(acc[i][j][r]);
      }
    }
  }
  score_epilogue(acc, a_src, a_dst, alo, ahi, m0, n0, wi, wj, quad, fr, M);
}

// ---------- 128x128-tile GEMM, f32 A input + fused scores (layer 1) ----------
__global__ __launch_bounds__(256) void gemm128_f32(
    const float* __restrict__ A, const u16* __restrict__ W,
    u16* __restrict__ C, const float* __restrict__ a_src,
    const float* __restrict__ a_dst, float* __restrict__ alo,
    float* __restrict__ ahi, int M, int Nout, int K) {
  __shared__ u16 As[128][40];
  __shared__ u16 Bs[128][40];
  const int t = threadIdx.x;
  const int m0 = blockIdx.y * 128, n0 = blockIdx.x * 128;
  const int rq = t >> 2, q = t & 3;
  const int w = t >> 6, lane = t & 63;
  const int wi = (w & 1) * 64, wj = (w >> 1) * 64;
  const int quad = lane >> 4, fr = lane & 15;

  f4v acc[4][4] = {};
  for (int k0 = 0; k0 < K; k0 += 32) {
    uint4 av[2], bv[2];
#pragma unroll
    for (int g = 0; g < 2; ++g) {
      int r = rq + g * 64;
      int m = m0 + r;
      if (m < M) {
        float4 f0 = *(const float4*)&A[(size_t)m * K + k0 + q * 8];
        float4 f1 = *(const float4*)&A[(size_t)m * K + k0 + q * 8 + 4];
        av[g].x = (unsigned)fb(f0.x) | ((unsigned)fb(f0.y) << 16);
        av[g].y = (unsigned)fb(f0.z) | ((unsigned)fb(f0.w) << 16);
        av[g].z = (unsigned)fb(f1.x) | ((unsigned)fb(f1.y) << 16);
        av[g].w = (unsigned)fb(f1.z) | ((unsigned)fb(f1.w) << 16);
      } else {
        av[g] = make_uint4(0, 0, 0, 0);
      }
      bv[g] = *(const uint4*)&W[(size_t)(n0 + r) * K + k0 + q * 8];
    }
    __syncthreads();
#pragma unroll
    for (int g = 0; g < 2; ++g) {
      *(uint4*)&As[rq + g * 64][q * 8] = av[g];
      *(uint4*)&Bs[rq + g * 64][q * 8] = bv[g];
    }
    __syncthreads();
    s8v af[4], bf_[4];
#pragma unroll
    for (int i = 0; i < 4; ++i) {
      af[i] = *(const s8v*)&As[wi + i * 16 + fr][quad * 8];
      bf_[i] = *(const s8v*)&Bs[wj + i * 16 + fr][quad * 8];
    }
#pragma unroll
    for (int i = 0; i < 4; ++i)
#pragma unroll
      for (int j = 0; j < 4; ++j)
        acc[i][j] =
            __builtin_amdgcn_mfma_f32_16x16x32_bf16(af[i], bf_[j], acc[i][j], 0, 0, 0);
  }
#pragma unroll
  for (int i = 0; i < 4; ++i) {
    int rbase = m0 + wi + i * 16 + quad * 4;
#pragma unroll
    for (int j = 0; j < 4; ++j) {
      int col = n0 + wj + j * 16 + fr;
#pragma unroll
      for (int r = 0; r < 4; ++r) {
        int row = rbase + r;
        if (row < M) C[(size_t)row * Nout + col] = fb(acc[i][j][r]);
      }
    }
  }
  score_epilogue(acc, a_src, a_dst, alo, ahi, m0, n0, wi, wj, quad, fr, M);
}

// ---------- 64x64-tile GEMM (layer 3, Nout=64) ----------
__global__ __launch_bounds__(256) void gemm_bf16(
    const u16* __restrict__ A, const u16* __restrict__ W,
    u16* __restrict__ C, int M, int Nout, int K) {
  __shared__ u16 As[64][40];
  __shared__ u16 Bs[64][40];
  const int t = threadIdx.x;
  const int m0 = blockIdx.y * 64, n0 = blockIdx.x * 64;
  const int r = t >> 2, c = t & 3;
  const int w = t >> 6, lane = t & 63;
  const int mi = (w & 1) * 32, ni = (w >> 1) * 32;
  const int quad = lane >> 4, fr = lane & 15;

  f4v c00{}, c01{}, c10{}, c11{};
  for (int k0 = 0; k0 < K; k0 += 32) {
    uint4 av = make_uint4(0, 0, 0, 0);
    int m = m0 + r;
    if (m < M) av = *(const uint4*)&A[(size_t)m * K + k0 + c * 8];
    uint4 bv = *(const uint4*)&W[(size_t)(n0 + r) * K + k0 + c * 8];
    __syncthreads();
    *(uint4*)&As[r][c * 8] = av;
    *(uint4*)&Bs[r][c * 8] = bv;
    __syncthreads();
    s8v a0 = *(const s8v*)&As[mi + fr][quad * 8];
    s8v a1 = *(const s8v*)&As[mi + 16 + fr][quad * 8];
    s8v b0 = *(const s8v*)&Bs[ni + fr][quad * 8];
    s8v b1 = *(const s8v*)&Bs[ni + 16 + fr][quad * 8];
    c00 = __builtin_amdgcn_mfma_f32_16x16x32_bf16(a0, b0, c00, 0, 0, 0);
    c01 = __builtin_amdgcn_mfma_f32_16x16x32_bf16(a0, b1, c01, 0, 0, 0);
    c10 = __builtin_amdgcn_mfma_f32_16x16x32_bf16(a1, b0, c10, 0, 0, 0);
    c11 = __builtin_amdgcn_mfma_f32_16x16x32_bf16(a1, b1, c11, 0, 0, 0);
  }
  const int col = n0 + ni + fr;
#pragma unroll
  for (int i = 0; i < 4; ++i) {
    int row = m0 + mi + quad * 4 + i;
    if (row < M) {
      C[(size_t)row * Nout + col] = fb(c00[i]);
      C[(size_t)row * Nout + col + 16] = fb(c01[i]);
    }
    int row2 = row + 16;
    if (row2 < M) {
      C[(size_t)row2 * Nout + col] = fb(c10[i]);
      C[(size_t)row2 * Nout + col + 16] = fb(c11[i]);
    }
  }
}

// ---------- CSR build ----------
__global__ void k_hist(const int* __restrict__ ei, int* __restrict__ deg) {
  int e = blockIdx.x * 256 + threadIdx.x;
  if (e >= EP_EDGES) return;
  int d = (e < N_EDGES) ? ei[N_EDGES + e] : e - N_EDGES;
  atomicAdd(&deg[d], 1);
}

__global__ void k_scan_local(const int* __restrict__ deg,
                             int* __restrict__ rowstart,
                             int* __restrict__ bsum) {
  __shared__ int sh[256];
  const int tid = threadIdx.x;
  const int i = blockIdx.x * 256 + tid;
  int v = (i < N_NODES) ? deg[i] : 0;
  sh[tid] = v;
  __syncthreads();
  for (int off = 1; off < 256; off <<= 1) {
    int add = (tid >= off) ? sh[tid - off] : 0;
    __syncthreads();
    sh[tid] += add;
    __syncthreads();
  }
  if (i < N_NODES) rowstart[i] = sh[tid] - v;
  if (tid == 255) bsum[blockIdx.x] = sh[255];
}

__global__ void k_scan_bsum(int* __restrict__ bsum, int* __restrict__ boff) {
  __shared__ int sh[256];
  const int tid = threadIdx.x;
  int v = (tid < NBLK_SCAN) ? bsum[tid] : 0;
  sh[tid] = v;
  __syncthreads();
  for (int off = 1; off < 256; off <<= 1) {
    int add = (tid >= off) ? sh[tid - off] : 0;
    __syncthreads();
    sh[tid] += add;
    __syncthreads();
  }
  boff[tid] = sh[tid] - v;
}

__global__ void k_scan_add(int* __restrict__ rowstart,
                           const int* __restrict__ boff) {
  int i = blockIdx.x * 256 + threadIdx.x;
  if (i < N_NODES) rowstart[i] += boff[i >> 8];
  if (i == N_NODES) rowstart[N_NODES] = EP_EDGES;
}

__global__ void k_scatter(const int* __restrict__ ei,
                          const int* __restrict__ rowstart,
                          int* __restrict__ fill, int* __restrict__ esrc) {
  int e = blockIdx.x * 256 + threadIdx.x;
  if (e >= EP_EDGES) return;
  int s, d;
  if (e < N_EDGES) { s = ei[e]; d = ei[N_EDGES + e]; }
  else             { s = d = e - N_EDGES; }
  int pos = rowstart[d] + atomicAdd(&fill[d], 1);
  esrc[pos] = s;
}

// ---------- per-node attention scores, H=1 ----------
__global__ __launch_bounds__(256) void attn_scores1(
    const u16* __restrict__ h, const float* __restrict__ a_src,
    const float* __restrict__ a_dst, float* __restrict__ alo,
    float* __restrict__ ahi) {
  const int t = threadIdx.x;
  const int n = blockIdx.x * 4 + (t >> 6);
  const int lane = t & 63;
  float v = bff(h[(size_t)n * 64 + lane]);
  float s = v * a_src[lane];
  float d = v * a_dst[lane];
#pragma unroll
  for (int off = 32; off; off >>= 1) {
    s += __shfl_xor(s, off, 64);
    d += __shfl_xor(d, off, 64);
  }
  if (lane == 0) {
    alo[n] = s;
    ahi[n] = d;
  }
}

// ---------- aggregation v3, H=4: one wave per dst, 4 ch/lane, unroll-8 ----
__global__ __launch_bounds__(64) void agg3_4(
    const int* __restrict__ rowstart, const int* __restrict__ esrc,
    const u16* __restrict__ hbuf, const float* __restrict__ alo,
    const float* __restrict__ ahi, const float* __restrict__ bias,
    u16* __restrict__ feat) {
  const int d = blockIdx.x;
  const int lane = threadIdx.x;
  const int head = lane >> 4;
  const int l16 = lane & 15;
  const int c = lane * 4;
  const int s0 = rowstart[d], s1 = rowstart[d + 1];
  const float ah = ahi[d * 4 + head];

  float sm = 0.f;
  for (int j = s0 + l16; j < s1; j += 16) {
    int s = esrc[j];
    float e = alo[s * 4 + head] + ah;
    e = e > 0.f ? e : 0.2f * e;
    sm += __expf(e);
  }
#pragma unroll
  for (int off = 8; off; off >>= 1) sm += __shfl_xor(sm, off, 64);
  const float linv = 1.f / (sm + 1e-16f);

  float o0 = 0.f, o1 = 0.f, o2 = 0.f, o3 = 0.f;
  for (int j = s0; j < s1; j += 8) {
    int ss[8];
    float wq[8];
#pragma unroll
    for (int q = 0; q < 8; ++q) {
      int jj = j + q;
      int sv = esrc[jj < EP_EDGES ? jj : EP_EDGES - 1];
      ss[q] = (jj < s1) ? sv : d;
    }
#pragma unroll
    for (int q = 0; q < 8; ++q) {
      float e = alo[ss[q] * 4 + head] + ah;
      e = e > 0.f ? e : 0.2f * e;
      wq[q] = (j + q < s1) ? __expf(e) * linv : 0.f;
    }
    uint2 hv[8];
#pragma unroll
    for (int q = 0; q < 8; ++q)
      hv[q] = *(const uint2*)&hbuf[(size_t)ss[q] * 256 + c];
#pragma unroll
    for (int q = 0; q < 8; ++q) {
      o0 += wq[q] * bfl(hv[q].x);
      o1 += wq[q] * bfh(hv[q].x);
      o2 += wq[q] * bfl(hv[q].y);
      o3 += wq[q] * bfh(hv[q].y);
    }
  }
  float4 bv = *(const float4*)&bias[c];
  float v0 = o0 + bv.x, v1 = o1 + bv.y, v2 = o2 + bv.z, v3 = o3 + bv.w;
  v0 = v0 > 0.f ? v0 : __expf(v0) - 1.f;
  v1 = v1 > 0.f ? v1 : __expf(v1) - 1.f;
  v2 = v2 > 0.f ? v2 : __expf(v2) - 1.f;
  v3 = v3 > 0.f ? v3 : __expf(v3) - 1.f;
  uint2 pv;
  pv.x = (unsigned)fb(v0) | ((unsigned)fb(v1) << 16);
  pv.y = (unsigned)fb(v2) | ((unsigned)fb(v3) << 16);
  *(uint2*)&feat[(size_t)d * 256 + c] = pv;
}

// ---------- aggregation v3, H=1 (f32 out), unroll-8 ----------
__global__ __launch_bounds__(64) void agg3_1(
    const int* __restrict__ rowstart, const int* __restrict__ esrc,
    const u16* __restrict__ hbuf, const float* __restrict__ alo,
    const float* __restrict__ ahi, const float* __restrict__ bias,
    float* __restrict__ feat) {
  const int d = blockIdx.x;
  const int t = threadIdx.x;
  const int s0 = rowstart[d], s1 = rowstart[d + 1];
  const float ah = ahi[d];

  float sm = 0.f;
  for (int j = s0 + t; j < s1; j += 64) {
    int s = esrc[j];
    float e = alo[s] + ah;
    e = e > 0.f ? e : 0.2f * e;
    sm += __expf(e);
  }
#pragma unroll
  for (int off = 32; off; off >>= 1) sm += __shfl_xor(sm, off, 64);
  const float linv = 1.f / (sm + 1e-16f);

  float o = 0.f;
  for (int j = s0; j < s1; j += 8) {
    int ss[8];
    float wq[8];
#pragma unroll
    for (int q = 0; q < 8; ++q) {
      int jj = j + q;
      int sv = esrc[jj < EP_EDGES ? jj : EP_EDGES - 1];
      ss[q] = (jj < s1) ? sv : d;
    }
#pragma unroll
    for (int q = 0; q < 8; ++q) {
      float e = alo[ss[q]] + ah;
      e = e > 0.f ? e : 0.2f * e;
      wq[q] = (j + q < s1) ? __expf(e) * linv : 0.f;
    }
    u16 hv[8];
#pragma unroll
    for (int q = 0; q < 8; ++q) hv[q] = hbuf[(size_t)ss[q] * 64 + t];
#pragma unroll
    for (int q = 0; q < 8; ++q) o += wq[q] * bff(hv[q]);
  }
  float v = o + bias[t];
  feat[(size_t)d * 64 + t] = v > 0.f ? v : __expf(v) - 1.f;
}

// ---------- segmented global mean pool (batch_idx sorted) ----------
__global__ __launch_bounds__(64) void pool_seg(
    const float* __restrict__ feat, const int* __restrict__ batch,
    float* __restrict__ gsum, float* __restrict__ gcnt) {
  const int b = blockIdx.x;
  const int t = threadIdx.x;
  int n0 = b * POOL_CHUNK;
  int n1 = n0 + POOL_CHUNK;
  if (n1 > N_NODES) n1 = N_NODES;
  if (n0 >= n1) return;
  int g = batch[n0];
  float acc = 0.f;
  int cnt = 0;
  for (int n = n0; n < n1; ++n) {
    int gn = batch[n];
    if (gn != g) {
      atomicAdd(&gsum[g * 64 + t], acc);
      if (t == 0) atomicAdd(&gcnt[g], (float)cnt);
      acc = 0.f; cnt = 0; g = gn;
    }
    acc += feat[(size_t)n * 64 + t];
    ++cnt;
  }
  atomicAdd(&gsum[g * 64 + t], acc);
  if (t == 0) atomicAdd(&gcnt[g], (float)cnt);
}

// ---------- fused MLP heads ----------
__global__ void heads(const float* __restrict__ gsum,
                      const float* __restrict__ gcnt,
                      const float* __restrict__ Wc1, const float* __restrict__ bc1,
                      const float* __restrict__ Wc2, const float* __restrict__ bc2,
                      const float* __restrict__ Wr1, const float* __restrict__ br1,
                      const float* __restrict__ Wr2, const float* __restrict__ br2,
                      float* __restrict__ out) {
  __shared__ float g[64];
  const int gi = blockIdx.x, j = threadIdx.x;
  float cnt = gcnt[gi];
  cnt = cnt < 1.f ? 1.f : cnt;
  g[j] = gsum[gi * 64 + j] / cnt;
  __syncthreads();
  float hc = bc1[j], hr = br1[j];
#pragma unroll 8
  for (int c = 0; c < 64; ++c) {
    float gv = g[c];
    hc += gv * Wc1[j * 64 + c];
    hr += gv * Wr1[j * 64 + c];
  }
  hc = fmaxf(hc, 0.f) * Wc2[j];
  hr = fmaxf(hr, 0.f) * Wr2[j];
#pragma unroll
  for (int off = 32; off; off >>= 1) {
    hc += __shfl_down(hc, off, 64);
    hr += __shfl_down(hr, off, 64);
  }
  if (j == 0) {
    out[gi] = hc + bc2[0];
    out[N_GRAPHS + gi] = hr + br2[0];
  }
}

extern "C" void kernel_launch(void* const* d_in, const int* in_sizes, int n_in,
                              void* d_out, int out_size, void* d_ws,
                              size_t ws_size, hipStream_t stream) {
  const float* x   = (const float*)d_in[0];
  const int* ei    = (const int*)d_in[1];
  const int* batch = (const int*)d_in[2];
  const float* W1  = (const float*)d_in[3];
  const float* as1 = (const float*)d_in[4];
  const float* ad1 = (const float*)d_in[5];
  const float* b1  = (const float*)d_in[6];
  const float* W2  = (const float*)d_in[7];
  const float* as2 = (const float*)d_in[8];
  const float* ad2 = (const float*)d_in[9];
  const float* b2  = (const float*)d_in[10];
  const float* W3  = (const float*)d_in[11];
  const float* as3 = (const float*)d_in[12];
  const float* ad3 = (const float*)d_in[13];
  const float* b3  = (const float*)d_in[14];
  const float* Wc1 = (const float*)d_in[15];
  const float* bc1 = (const float*)d_in[16];
  const float* Wc2 = (const float*)d_in[17];
  const float* bc2 = (const float*)d_in[18];
  const float* Wr1 = (const float*)d_in[19];
  const float* br1 = (const float*)d_in[20];
  const float* Wr2 = (const float*)d_in[21];
  const float* br2 = (const float*)d_in[22];
  float* out = (float*)d_out;

  // ---- workspace layout ----
  float* ws = (float*)d_ws;
  u16* h_buf = (u16*)ws;
  float* p = ws + (size_t)N_NODES * 128;
  u16* featb = (u16*)p;
  p += (size_t)N_NODES * 128;
  u16* W1b = (u16*)p; p += 16384;
  u16* W2b = (u16*)p; p += 32768;
  u16* W3b = (u16*)p; p += 8192;
  float* feat3 = p;   p += (size_t)N_NODES * 64;
  float* alo   = p;   p += (size_t)N_NODES * 4;
  float* ahi   = p;   p += (size_t)N_NODES * 4;
  int* rowstart = (int*)p; p += (N_NODES + 4);
  int* esrc    = (int*)p;  p += EP_EDGES;
  float* gsum  = p;   p += N_GRAPHS * 64;
  float* gcnt  = p;
  int* deg  = (int*)alo;
  int* fill = (int*)alo + N_NODES;
  int* bsum = (int*)gsum;
  int* boff = (int*)gsum + 256;

  // ---- CSR build ----
  hipMemsetAsync(deg, 0, (size_t)2 * N_NODES * 4, stream);  // deg + fill
  const int eblk = (EP_EDGES + 255) / 256;
  k_hist<<<eblk, 256, 0, stream>>>(ei, deg);
  k_scan_local<<<NBLK_SCAN, 256, 0, stream>>>(deg, rowstart, bsum);
  k_scan_bsum<<<1, 256, 0, stream>>>(bsum, boff);
  k_scan_add<<<(N_NODES + 256) / 256, 256, 0, stream>>>(rowstart, boff);
  k_scatter<<<eblk, 256, 0, stream>>>(ei, rowstart, fill, esrc);

  // ---- weight bf16 conversion ----
  f2bw<<<(W_N3 + 255) / 256, 256, 0, stream>>>(W1, W2, W3, W1b, W2b, W3b);

  const int MB128 = (N_NODES + 127) / 128;
  const int MB64 = (N_NODES + 63) / 64;
  // ---- layer 1 (f32 x input; scores fused) ----
  gemm128_f32<<<dim3(2, MB128), 256, 0, stream>>>(x, W1b, h_buf, as1, ad1, alo,
                                                  ahi, N_NODES, 256, 128);
  agg3_4<<<N_NODES, 64, 0, stream>>>(rowstart, esrc, h_buf, alo, ahi, b1,
                                     featb);
  // ---- layer 2 (scores fused) ----
  gemm128<<<dim3(2, MB128), 256, 0, stream>>>(featb, W2b, h_buf, as2, ad2, alo,
                                              ahi, N_NODES, 256, 256);
  agg3_4<<<N_NODES, 64, 0, stream>>>(rowstart, esrc, h_buf, alo, ahi, b2,
                                     featb);
  // ---- layer 3 ----
  gemm_bf16<<<dim3(1, MB64), 256, 0, stream>>>(featb, W3b, h_buf, N_NODES, 64, 256);
  attn_scores1<<<N_NODES / 4, 256, 0, stream>>>(h_buf, as3, ad3, alo, ahi);
  agg3_1<<<N_NODES, 64, 0, stream>>>(rowstart, esrc, h_buf, alo, ahi, b3,
                                     feat3);

  // ---- segmented mean pool + heads ----
  hipMemsetAsync(gsum, 0, (size_t)(N_GRAPHS * 64 + N_GRAPHS) * 4, stream);
  pool_seg<<<N_GRAPHS, 64, 0, stream>>>(feat3, batch, gsum, gcnt);
  heads<<<N_GRAPHS, 64, 0, stream>>>(gsum, gcnt, Wc1, bc1, Wc2, bc2, Wr1, br1,
                                     Wr2, br2, out);
}